// Round 1
// baseline (236.565 us; speedup 1.0000x reference)
//
#include <hip/hip_runtime.h>

#define NHEAD 32
#define LSEQ  2048
#define DIM   64
#define QBLK  64
#define KBLK  64
#define NTILE (LSEQ / KBLK)

typedef float  f32x4  __attribute__((ext_vector_type(4)));
typedef __bf16 bf16x8 __attribute__((ext_vector_type(8)));
typedef unsigned short u16;

__device__ __forceinline__ u16 f2bf(float f) {
    return __builtin_bit_cast(u16, (__bf16)f);   // HW RNE convert
}
__device__ __forceinline__ void st4bf(u16* p, float4 v) {
    union { u16 h[4]; uint2 q; } pk;
    pk.h[0] = f2bf(v.x); pk.h[1] = f2bf(v.y);
    pk.h[2] = f2bf(v.z); pk.h[3] = f2bf(v.w);
    *(uint2*)p = pk.q;
}

// Workgroup barrier WITHOUT the vmcnt(0) drain that __syncthreads() emits:
// in-flight global prefetch loads survive the barrier. lgkmcnt(0) commits
// this wave's LDS writes (and completes its LDS reads) first; the "memory"
// clobber pins LDS/global ops on their side of the barrier.
#define WG_BARRIER() asm volatile("s_waitcnt lgkmcnt(0)\n\ts_barrier" ::: "memory")

// 0.125 (1/sqrt(64)) * log2(e): softmax computed in exp2 domain
#define QSCALE 0.18033688011112042f
// defer-max threshold (exp2 domain): p bounded by 2^8, bf16/f32 tolerate it
#define RESCALE_THR 8.0f

__launch_bounds__(256, 4)
__global__ void attn_fused_kernel(const float* __restrict__ Q,
                                  const float* __restrict__ K,
                                  const float* __restrict__ V,
                                  const float* __restrict__ Msk,
                                  float* __restrict__ out,
                                  float* __restrict__ loss)
{
    // double-buffered K and V^T tiles, pitch 72 hw (144 B = 16B-aligned rows,
    // b128 reads at banks 4*(lr+lq) mod 32 -> 8 lanes per 4-bank group = min)
    __shared__ __align__(16) u16 lds_k[2][64][72];   // K tile  [k_row][c]
    __shared__ __align__(16) u16 lds_v[2][64][72];   // V^T     [d][perm(k)]

    const int t  = threadIdx.x;
    // bijective XCD-chunked swizzle: 1024 blocks, 8 XCDs, 128-block chunks
    const int wg   = ((int)blockIdx.x & 7) * 128 + ((int)blockIdx.x >> 3);
    const int head = wg >> 5;
    const int qb   = wg & 31;
    const int qbase = qb * QBLK;
    const int w  = t >> 6;
    const int l  = t & 63;
    const int lr = l & 15;   // A-row / B-col index
    const int lq = l >> 4;   // k-group / D-row-group

    const size_t hoff = (size_t)head * LSEQ * DIM;
    const int qg = qbase + 16 * w + lr;          // this lane's q row

    // ---- Q fragments for q row = qg, scale folded in (slots c = 32s + 8lq + j) ----
    bf16x8 qf[2];
#pragma unroll
    for (int s = 0; s < 2; ++s) {
        const float* src = Q + hoff + (size_t)qg * DIM + 32 * s + 8 * lq;
        float4 a = *(const float4*)(src);
        float4 b = *(const float4*)(src + 4);
        union { u16 h[8]; bf16x8 v; } u;
        u.h[0] = f2bf(a.x * QSCALE); u.h[1] = f2bf(a.y * QSCALE);
        u.h[2] = f2bf(a.z * QSCALE); u.h[3] = f2bf(a.w * QSCALE);
        u.h[4] = f2bf(b.x * QSCALE); u.h[5] = f2bf(b.y * QSCALE);
        u.h[6] = f2bf(b.z * QSCALE); u.h[7] = f2bf(b.w * QSCALE);
        qf[s] = u.v;
    }

    f32x4 acc[4];                 // O^T fragments: col=q(=lr), row d = 16dt+4lq+r
#pragma unroll
    for (int dt = 0; dt < 4; ++dt) acc[dt] = (f32x4){0.f, 0.f, 0.f, 0.f};
    float mrun = -1e30f, lrun = 0.f, la2 = 0.f, lam = 0.f;

    // ---- register staging buffers (T14 prefetch: loads for tile kb+1 are
    //      issued before the barrier and land during compute of tile kb) ----
    float4 kr[4];                 // K: 4 rows of float4 (4 d at one k-row)
    float4 vr[4];                 // V: 4 k at one d (gathered dword loads)
    const float* Kg = K + hoff;
    const float* Vg = V + hoff;
    const int krow0 = t >> 4;           // K stage row (+16i)
    const int kcol  = (t & 15) * 4;     // K stage col

    auto issue = [&](int kb) {
        const float* kp = Kg + (size_t)(kb * KBLK) * DIM;
        const float* vp = Vg + (size_t)(kb * KBLK) * DIM;
#pragma unroll
        for (int i = 0; i < 4; ++i)
            kr[i] = *(const float4*)(kp + (krow0 + 16 * i) * DIM + kcol);
        // lane handles d = l, k = 4w+16i+j: each dword load is a wave-contiguous
        // 256B segment; LDS write becomes a conflict-free b64 (no b16 scatter)
#pragma unroll
        for (int i = 0; i < 4; ++i) {
            const int kk = 4 * w + 16 * i;
            vr[i].x = vp[(kk + 0) * DIM + l];
            vr[i].y = vp[(kk + 1) * DIM + l];
            vr[i].z = vp[(kk + 2) * DIM + l];
            vr[i].w = vp[(kk + 3) * DIM + l];
        }
    };

    issue(0);
    int cur = 0;

    for (int kb = 0; kb < NTILE; ++kb) {
        const int kbase = kb * KBLK;

        // ---- mask for this tile: straight to registers (single-use data —
        //      no LDS round-trip, no bf16 loss), consumed after the S MFMAs ----
        f32x4 mreg[4];
        {
            const float* mp_ = Msk + (size_t)qg * LSEQ + kbase + 4 * lq;
#pragma unroll
            for (int m = 0; m < 4; ++m)
                mreg[m] = *(const f32x4*)(mp_ + 16 * m);
        }

        // ---- write staged tile kb (regs -> LDS, fp32 -> bf16) ----
#pragma unroll
        for (int i = 0; i < 4; ++i)
            st4bf(&lds_k[cur][krow0 + 16 * i][kcol], kr[i]);
        // V^T row layout is k-permuted: pos(k) = 32(k>>5) + 8((k>>2)&3)
        //   + 4((k>>4)&1) + (k&3), so the PV fragment {32mp+4lq+j, 32mp+16+4lq+j}
        //   is 8 CONTIGUOUS hw -> one ds_read_b128.
#pragma unroll
        for (int i = 0; i < 4; ++i) {
            const int kq = w + 4 * i;   // k>>2 of this thread's 4 staged k
            const int p0 = 32 * (kq >> 3) + 8 * (kq & 3) + 4 * ((kq >> 2) & 1);
            st4bf(&lds_v[cur][l][p0], vr[i]);
        }

        if (kb + 1 < NTILE) issue(kb + 1);   // prefetch survives WG_BARRIER
        WG_BARRIER();

        // ---- S^T = K * Q^T : D col=q(=lr), row k = 16m + 4lq + r ----
        f32x4 S[4];
#pragma unroll
        for (int m = 0; m < 4; ++m) {
            bf16x8 kf0 = *(const bf16x8*)&lds_k[cur][16 * m + lr][8 * lq];
            bf16x8 kf1 = *(const bf16x8*)&lds_k[cur][16 * m + lr][32 + 8 * lq];
            f32x4 z = (f32x4){0.f, 0.f, 0.f, 0.f};
            z = __builtin_amdgcn_mfma_f32_16x16x32_bf16(kf0, qf[0], z, 0, 0, 0);
            z = __builtin_amdgcn_mfma_f32_16x16x32_bf16(kf1, qf[1], z, 0, 0, 0);
            S[m] = z;
        }

        // ---- in-lane online softmax with defer-max (T13) ----
        float tm = fmaxf(fmaxf(fmaxf(S[0][0], S[0][1]), fmaxf(S[0][2], S[0][3])),
                         fmaxf(fmaxf(S[1][0], S[1][1]), fmaxf(S[1][2], S[1][3])));
        tm = fmaxf(tm, fmaxf(fmaxf(fmaxf(S[2][0], S[2][1]), fmaxf(S[2][2], S[2][3])),
                             fmaxf(fmaxf(S[3][0], S[3][1]), fmaxf(S[3][2], S[3][3]))));
        tm = fmaxf(tm, __shfl_xor(tm, 16));
        tm = fmaxf(tm, __shfl_xor(tm, 32));
        if (!__all(tm - mrun <= RESCALE_THR)) {      // wave-uniform branch
            const float mn = fmaxf(mrun, tm);
            const float al = __builtin_amdgcn_exp2f(mrun - mn);
            mrun = mn;
            lrun *= al; la2 *= al * al; lam *= al;
#pragma unroll
            for (int dt = 0; dt < 4; ++dt) acc[dt] *= al;
        }

        float psum = 0.f, pp2 = 0.f, ppm = 0.f;
        u16 pb[16];
#pragma unroll
        for (int m = 0; m < 4; ++m) {
#pragma unroll
            for (int r = 0; r < 4; ++r) {
                float p = __builtin_amdgcn_exp2f(S[m][r] - mrun);
                psum += p;
                pp2  += p * p;
                ppm  += p * mreg[m][r];
                pb[4 * m + r] = f2bf(p);
            }
        }
        lrun += psum; la2 += pp2; lam += ppm;

        // ---- O^T += V^T * P : A=V^T (row=d), B=P packed with matching k-slots ----
        bf16x8 pf[2];
#pragma unroll
        for (int mp = 0; mp < 2; ++mp) {
            union { u16 h[8]; bf16x8 v; } u;
#pragma unroll
            for (int j = 0; j < 4; ++j) { u.h[j] = pb[8 * mp + j]; u.h[4 + j] = pb[8 * mp + 4 + j]; }
            pf[mp] = u.v;
        }
#pragma unroll
        for (int dt = 0; dt < 4; ++dt) {
#pragma unroll
            for (int mp = 0; mp < 2; ++mp) {
                bf16x8 vf = *(const bf16x8*)&lds_v[cur][16 * dt + lr][32 * mp + 8 * lq];
                acc[dt] = __builtin_amdgcn_mfma_f32_16x16x32_bf16(vf, pf[mp], acc[dt], 0, 0, 0);
            }
        }
        cur ^= 1;
    }

    // ---- reduce per-lane row partials across the 4 k-groups (lanes xor 16,32) ----
#pragma unroll
    for (int off = 16; off <= 32; off <<= 1) {
        lrun += __shfl_xor(lrun, off);
        la2  += __shfl_xor(la2,  off);
        lam  += __shfl_xor(lam,  off);
    }

    const float inv = 1.0f / lrun;

    // ---- context write: float4 of 4 consecutive d per acc tile ----
#pragma unroll
    for (int dt = 0; dt < 4; ++dt) {
        float4 o;
        o.x = acc[dt][0] * inv; o.y = acc[dt][1] * inv;
        o.z = acc[dt][2] * inv; o.w = acc[dt][3] * inv;
        *(float4*)(out + hoff + (size_t)qg * DIM + 16 * dt + 4 * lq) = o;
    }

    // ---- loss partial: one value per q row (keep lq==0 lanes), wave-reduce, one atomic ----
    float part = la2 * inv * inv - 2.0f * lam * inv;
    part = (l < 16) ? part : 0.f;
#pragma unroll
    for (int off = 1; off <= 8; off <<= 1) part += __shfl_xor(part, off);
    if (l == 0) atomicAdd(loss, part);
}

// loss += 32 * sum(mask^2), fp32 (dominant loss term, kept near-exact)
__global__ void masksq_kernel(const float* __restrict__ Msk, float* __restrict__ loss)
{
    __shared__ float red[4];
    float s = 0.f;
    const size_t n4 = (size_t)LSEQ * LSEQ / 4;
    for (size_t i = (size_t)blockIdx.x * blockDim.x + threadIdx.x; i < n4;
         i += (size_t)gridDim.x * blockDim.x) {
        float4 v = ((const float4*)Msk)[i];
        s += v.x * v.x + v.y * v.y + v.z * v.z + v.w * v.w;
    }
#pragma unroll
    for (int off = 1; off <= 32; off <<= 1) s += __shfl_xor(s, off);
    if ((threadIdx.x & 63) == 0) red[threadIdx.x >> 6] = s;
    __syncthreads();
    if (threadIdx.x == 0) {
        float tot = red[0] + red[1] + red[2] + red[3];
        atomicAdd(loss, 32.0f * tot);
    }
}

extern "C" void kernel_launch(void* const* d_in, const int* in_sizes, int n_in,
                              void* d_out, int out_size, void* d_ws, size_t ws_size,
                              hipStream_t stream)
{
    const float* Q   = (const float*)d_in[0];
    const float* K   = (const float*)d_in[1];
    const float* V   = (const float*)d_in[2];
    const float* Msk = (const float*)d_in[3];
    float* out  = (float*)d_out;
    float* loss = out + (size_t)NHEAD * LSEQ * DIM;  // element 4194304

    hipMemsetAsync(loss, 0, sizeof(float), stream);
    masksq_kernel<<<256, 256, 0, stream>>>(Msk, loss);
    attn_fused_kernel<<<NHEAD * (LSEQ / QBLK), 256, 0, stream>>>(Q, K, V, Msk, out, loss);
}

// Round 2
// 147.643 us; speedup vs baseline: 1.6023x; 1.6023x over previous
//
#include <hip/hip_runtime.h>

#define NHEAD 32
#define LSEQ  2048
#define DIM   64
#define QBLK  64
#define KBLK  64
#define NTILE (LSEQ / KBLK)

typedef float  f32x4  __attribute__((ext_vector_type(4)));
typedef __bf16 bf16x8 __attribute__((ext_vector_type(8)));
typedef unsigned short u16;

__device__ __forceinline__ u16 f2bf(float f) {
    return __builtin_bit_cast(u16, (__bf16)f);   // HW RNE convert
}
__device__ __forceinline__ void st4bf(u16* p, float4 v) {
    union { u16 h[4]; uint2 q; } pk;
    pk.h[0] = f2bf(v.x); pk.h[1] = f2bf(v.y);
    pk.h[2] = f2bf(v.z); pk.h[3] = f2bf(v.w);
    *(uint2*)p = pk.q;
}
// combine two 8B LDS reads into one bf16x8 fragment (slots 0-3 = a, 4-7 = b)
__device__ __forceinline__ bf16x8 comb64(const u16* a, const u16* b) {
    union { uint2 q[2]; bf16x8 v; } u;
    u.q[0] = *(const uint2*)a;
    u.q[1] = *(const uint2*)b;
    return u.v;
}

// 0.125 (1/sqrt(64)) * log2(e): softmax computed in exp2 domain
#define QSCALE 0.18033688011112042f
// defer-max threshold (exp2 domain): p bounded by 2^8
#define RESCALE_THR 8.0f

__launch_bounds__(256, 4)
__global__ void attn_fused_kernel(const float* __restrict__ Q,
                                  const float* __restrict__ K,
                                  const float* __restrict__ V,
                                  const float* __restrict__ Msk,
                                  float* __restrict__ out,
                                  float* __restrict__ loss)
{
    // pitch 72 hw for K (16B-aligned b128 rows); pitch 68 hw for v (b64, odd-dw bank spread)
    __shared__ __align__(16) u16 lds_k[64][72];   // K tile  [k_row][c]           (bf16)
    __shared__ __align__(16) u16 lds_v[64][68];   // V^T     [d][k_row]           (bf16)

    const int t  = threadIdx.x;
    // bijective XCD-chunked swizzle: 1024 blocks, 8 XCDs, 128-block chunks
    const int wg   = ((int)blockIdx.x & 7) * 128 + ((int)blockIdx.x >> 3);
    const int head = wg >> 5;
    const int qb   = wg & 31;
    const int qbase = qb * QBLK;
    const int w  = t >> 6;
    const int l  = t & 63;
    const int lr = l & 15;   // A-row / B-col index
    const int lq = l >> 4;   // k-group / D-row-group

    const size_t hoff = (size_t)head * LSEQ * DIM;
    const int qg = qbase + 16 * w + lr;          // this lane's q row (B-col side)

    // ---- Q fragments for q row = qg, scale folded in (slots c = 32s + 8lq + j) ----
    bf16x8 qf[2];
#pragma unroll
    for (int s = 0; s < 2; ++s) {
        const float* src = Q + hoff + (size_t)qg * DIM + 32 * s + 8 * lq;
        float4 a = *(const float4*)(src);
        float4 b = *(const float4*)(src + 4);
        union { u16 h[8]; bf16x8 v; } u;
        u.h[0] = f2bf(a.x * QSCALE); u.h[1] = f2bf(a.y * QSCALE);
        u.h[2] = f2bf(a.z * QSCALE); u.h[3] = f2bf(a.w * QSCALE);
        u.h[4] = f2bf(b.x * QSCALE); u.h[5] = f2bf(b.y * QSCALE);
        u.h[6] = f2bf(b.z * QSCALE); u.h[7] = f2bf(b.w * QSCALE);
        qf[s] = u.v;
    }

    f32x4 acc[4];                 // O^T fragments: col=q(=lr), row d = 16dt+4lq+r
#pragma unroll
    for (int dt = 0; dt < 4; ++dt) acc[dt] = (f32x4){0.f, 0.f, 0.f, 0.f};
    float mrun = -1e30f, lrun = 0.f, la2 = 0.f, lam = 0.f;

    for (int kb = 0; kb < NTILE; ++kb) {
        const int kbase = kb * KBLK;
        __syncthreads();          // previous tile's LDS reads done before restage

        // ---- mask straight to registers (single-use data, fixed lane mapping:
        //      no LDS round-trip, no bf16 cvt, no bank conflicts, fp32 exact) ----
        f32x4 mreg[4];
        {
            const float* mp_ = Msk + (size_t)qg * LSEQ + kbase + 4 * lq;
#pragma unroll
            for (int m = 0; m < 4; ++m)
                mreg[m] = *(const f32x4*)(mp_ + 16 * m);
        }

        // ---- stage K, V^T tiles (fp32 -> bf16) ----
        {
            const float* Kg = K + hoff + (size_t)kbase * DIM;
            const float* Vg = V + hoff + (size_t)kbase * DIM;
#pragma unroll
            for (int i = 0; i < 4; ++i) {
                const int id = t + 256 * i;
                const int r = id >> 4, c = (id & 15) * 4;
                float4 kv = *(const float4*)(Kg + r * DIM + c);
                float4 vv = *(const float4*)(Vg + r * DIM + c);
                st4bf(&lds_k[r][c], kv);
                lds_v[c + 0][r] = f2bf(vv.x);
                lds_v[c + 1][r] = f2bf(vv.y);
                lds_v[c + 2][r] = f2bf(vv.z);
                lds_v[c + 3][r] = f2bf(vv.w);
            }
        }
        __syncthreads();

        // ---- S^T = K * Q^T : D col=q(=lr), row k = 16m + 4lq + r ----
        f32x4 S[4];
#pragma unroll
        for (int m = 0; m < 4; ++m) {
            bf16x8 kf0 = *(const bf16x8*)&lds_k[16 * m + lr][8 * lq];
            bf16x8 kf1 = *(const bf16x8*)&lds_k[16 * m + lr][32 + 8 * lq];
            f32x4 z = (f32x4){0.f, 0.f, 0.f, 0.f};
            z = __builtin_amdgcn_mfma_f32_16x16x32_bf16(kf0, qf[0], z, 0, 0, 0);
            z = __builtin_amdgcn_mfma_f32_16x16x32_bf16(kf1, qf[1], z, 0, 0, 0);
            S[m] = z;
        }

        // ---- in-lane online softmax with defer-max (T13) ----
        float tm = fmaxf(fmaxf(fmaxf(S[0][0], S[0][1]), fmaxf(S[0][2], S[0][3])),
                         fmaxf(fmaxf(S[1][0], S[1][1]), fmaxf(S[1][2], S[1][3])));
        tm = fmaxf(tm, fmaxf(fmaxf(fmaxf(S[2][0], S[2][1]), fmaxf(S[2][2], S[2][3])),
                             fmaxf(fmaxf(S[3][0], S[3][1]), fmaxf(S[3][2], S[3][3]))));
        tm = fmaxf(tm, __shfl_xor(tm, 16));
        tm = fmaxf(tm, __shfl_xor(tm, 32));
        if (!__all(tm - mrun <= RESCALE_THR)) {      // wave-uniform branch
            const float mn = fmaxf(mrun, tm);
            const float al = __builtin_amdgcn_exp2f(mrun - mn);
            mrun = mn;
            lrun *= al; la2 *= al * al; lam *= al;
#pragma unroll
            for (int dt = 0; dt < 4; ++dt) acc[dt] *= al;
        }

        float psum = 0.f, pp2 = 0.f, ppm = 0.f;
        u16 pb[16];
#pragma unroll
        for (int m = 0; m < 4; ++m) {
#pragma unroll
            for (int r = 0; r < 4; ++r) {
                float p = __builtin_amdgcn_exp2f(S[m][r] - mrun);
                psum += p;
                pp2  += p * p;
                ppm  += p * mreg[m][r];
                pb[4 * m + r] = f2bf(p);
            }
        }
        lrun += psum; la2 += pp2; lam += ppm;

        // ---- O^T += V^T * P : A=V^T (row=d), B=P packed with matching k-slots ----
        bf16x8 pf[2];
#pragma unroll
        for (int mp = 0; mp < 2; ++mp) {
            union { u16 h[8]; bf16x8 v; } u;
#pragma unroll
            for (int j = 0; j < 4; ++j) { u.h[j] = pb[8 * mp + j]; u.h[4 + j] = pb[8 * mp + 4 + j]; }
            pf[mp] = u.v;
        }
#pragma unroll
        for (int dt = 0; dt < 4; ++dt) {
#pragma unroll
            for (int mp = 0; mp < 2; ++mp) {
                bf16x8 vf = comb64(&lds_v[16 * dt + lr][32 * mp + 4 * lq],
                                   &lds_v[16 * dt + lr][32 * mp + 16 + 4 * lq]);
                acc[dt] = __builtin_amdgcn_mfma_f32_16x16x32_bf16(vf, pf[mp], acc[dt], 0, 0, 0);
            }
        }
    }

    // ---- reduce per-lane row partials across the 4 k-groups (lanes xor 16,32) ----
#pragma unroll
    for (int off = 16; off <= 32; off <<= 1) {
        lrun += __shfl_xor(lrun, off);
        la2  += __shfl_xor(la2,  off);
        lam  += __shfl_xor(lam,  off);
    }

    const float inv = 1.0f / lrun;

    // ---- context write: float4 of 4 consecutive d per acc tile ----
#pragma unroll
    for (int dt = 0; dt < 4; ++dt) {
        float4 o;
        o.x = acc[dt][0] * inv; o.y = acc[dt][1] * inv;
        o.z = acc[dt][2] * inv; o.w = acc[dt][3] * inv;
        *(float4*)(out + hoff + (size_t)qg * DIM + 16 * dt + 4 * lq) = o;
    }

    // ---- loss partial: one value per q row (keep lq==0 lanes), wave-reduce, one atomic ----
    float part = la2 * inv * inv - 2.0f * lam * inv;
    part = (l < 16) ? part : 0.f;
#pragma unroll
    for (int off = 1; off <= 8; off <<= 1) part += __shfl_xor(part, off);
    if (l == 0) atomicAdd(loss, part);
}

// loss += 32 * sum(mask^2), fp32 (dominant loss term, kept near-exact)
__global__ void masksq_kernel(const float* __restrict__ Msk, float* __restrict__ loss)
{
    __shared__ float red[4];
    float s = 0.f;
    const size_t n4 = (size_t)LSEQ * LSEQ / 4;
    for (size_t i = (size_t)blockIdx.x * blockDim.x + threadIdx.x; i < n4;
         i += (size_t)gridDim.x * blockDim.x) {
        float4 v = ((const float4*)Msk)[i];
        s += v.x * v.x + v.y * v.y + v.z * v.z + v.w * v.w;
    }
#pragma unroll
    for (int off = 1; off <= 32; off <<= 1) s += __shfl_xor(s, off);
    if ((threadIdx.x & 63) == 0) red[threadIdx.x >> 6] = s;
    __syncthreads();
    if (threadIdx.x == 0) {
        float tot = red[0] + red[1] + red[2] + red[3];
        atomicAdd(loss, 32.0f * tot);
    }
}

extern "C" void kernel_launch(void* const* d_in, const int* in_sizes, int n_in,
                              void* d_out, int out_size, void* d_ws, size_t ws_size,
                              hipStream_t stream)
{
    const float* Q   = (const float*)d_in[0];
    const float* K   = (const float*)d_in[1];
    const float* V   = (const float*)d_in[2];
    const float* Msk = (const float*)d_in[3];
    float* out  = (float*)d_out;
    float* loss = out + (size_t)NHEAD * LSEQ * DIM;  // element 4194304

    hipMemsetAsync(loss, 0, sizeof(float), stream);
    masksq_kernel<<<256, 256, 0, stream>>>(Msk, loss);
    attn_fused_kernel<<<NHEAD * (LSEQ / QBLK), 256, 0, stream>>>(Q, K, V, Msk, out, loss);
}